// Round 3
// baseline (419.553 us; speedup 1.0000x reference)
//
#include <hip/hip_runtime.h>

#define B_SZ 8
#define N_SZ 4096
#define M_SZ 2048
#define D_SZ 512

typedef __attribute__((ext_vector_type(8))) short bf16x8;
typedef __attribute__((ext_vector_type(4))) float f32x4;
typedef __attribute__((address_space(1))) const void* gptr1;
typedef __attribute__((address_space(3))) void* lptr3;

__device__ __forceinline__ unsigned short f2bf(float x) {
    unsigned int u = __builtin_bit_cast(unsigned int, x);
    u += 0x7fffu + ((u >> 16) & 1u);
    return (unsigned short)(u >> 16);
}

// ---------- generic 128x128 B^T GEMM mainloop (bf16 in, fp32 acc) ----------
__device__ __forceinline__ void bt_mainloop(
    const unsigned short* __restrict__ A, const unsigned short* __restrict__ Bt,
    int lda, int ldb, int rowBase, int colBase, int K,
    unsigned short* As, unsigned short* Bs, f32x4 acc[4][4])
{
    const int tid  = threadIdx.x;
    const int lane = tid & 63;
    const int w    = tid >> 6;
    const int wr   = (w >> 1) * 64;
    const int wc   = (w & 1) * 64;
    const int lr   = lane & 15;
    const int kq   = lane >> 4;

    const int srow0 = w * 16 + (lane >> 2);
    const int skk   = (lane & 3) * 8;

    for (int k0 = 0; k0 < K; k0 += 32) {
#pragma unroll
        for (int j = 0; j < 2; ++j) {
            const unsigned short* ga = A  + (size_t)(rowBase + srow0 + j * 64) * lda + (k0 + skk);
            const unsigned short* gb = Bt + (size_t)(colBase + srow0 + j * 64) * ldb + (k0 + skk);
            __builtin_amdgcn_global_load_lds((gptr1)ga, (lptr3)(As + (j * 4 + w) * 512), 16, 0, 0);
            __builtin_amdgcn_global_load_lds((gptr1)gb, (lptr3)(Bs + (j * 4 + w) * 512), 16, 0, 0);
        }
        asm volatile("s_waitcnt vmcnt(0)" ::: "memory");
        __syncthreads();

        bf16x8 af[4], bq[4];
#pragma unroll
        for (int i = 0; i < 4; ++i) {
            af[i] = *(const bf16x8*)(As + (wr + i * 16 + lr) * 32 + kq * 8);
            bq[i] = *(const bf16x8*)(Bs + (wc + i * 16 + lr) * 32 + kq * 8);
        }
#pragma unroll
        for (int mi = 0; mi < 4; ++mi)
#pragma unroll
            for (int ni = 0; ni < 4; ++ni)
                acc[mi][ni] = __builtin_amdgcn_mfma_f32_16x16x32_bf16(af[mi], bq[ni], acc[mi][ni], 0, 0, 0);
        __syncthreads();
    }
}

// ---------- prep: t1 -> t1bf; |t1[m]| -> invs; b.t1[m] -> c2; copy t1 to out right half;
// ---------- zero out left half, L, SS ----------
__global__ __launch_bounds__(256) void prep_t_k(
    const float* __restrict__ text, const float* __restrict__ bias,
    unsigned short* __restrict__ t1bf, float* __restrict__ invs, float* __restrict__ c2,
    float* __restrict__ out, float* __restrict__ L, float* __restrict__ SS)
{
    const int m = blockIdx.x;
    const int t = threadIdx.x;  // 256
    const float* t1 = text + (size_t)M_SZ * D_SZ;
    float2 v = ((const float2*)(t1 + (size_t)m * D_SZ))[t];
    float2 bb = ((const float2*)bias)[t];
    float s = v.x * v.x + v.y * v.y;
    float c = v.x * bb.x + v.y * bb.y;
#pragma unroll
    for (int off = 32; off > 0; off >>= 1) { s += __shfl_down(s, off); c += __shfl_down(c, off); }
    __shared__ float ps[4], pc[4];
    if ((t & 63) == 0) { ps[t >> 6] = s; pc[t >> 6] = c; }
    __syncthreads();
    if (t == 0) {
        float norm = fmaxf(sqrtf(ps[0] + ps[1] + ps[2] + ps[3]), 1e-8f);
        invs[m] = 1.f / norm;
        c2[m] = pc[0] + pc[1] + pc[2] + pc[3];
    }
    ushort2 pk; pk.x = f2bf(v.x); pk.y = f2bf(v.y);
    ((ushort2*)(t1bf + (size_t)m * D_SZ))[t] = pk;
#pragma unroll
    for (int b = 0; b < B_SZ; ++b) {
        ((float2*)(out + ((size_t)(b * M_SZ + m)) * (2 * D_SZ) + D_SZ))[t] = v;
        ((float2*)(out + ((size_t)(b * M_SZ + m)) * (2 * D_SZ)))[t] = (float2){0.f, 0.f};
    }
    if (m < 64) L[m * 256 + t] = 0.f;
    if (m < 128) SS[m * 256 + t] = 0.f;
}

// ---------- prep: W fp32 [d][e] -> Wbf bf16 [d][e] (straight) and Wt bf16 [e][d] (transposed) ----------
__global__ __launch_bounds__(256) void prep_w_k(
    const float* __restrict__ W, unsigned short* __restrict__ Wt,
    unsigned short* __restrict__ Wbf)
{
    const int dt = blockIdx.x, et = blockIdx.y;
    const int t = threadIdx.x;
    __shared__ unsigned short tile[64][72];
    const int rr = t >> 4;
    const int cc = (t & 15) * 4;
#pragma unroll
    for (int p = 0; p < 4; ++p) {
        const int d = p * 16 + rr;
        const float4 v = *(const float4*)(W + (size_t)(dt * 64 + d) * D_SZ + et * 64 + cc);
        ushort4 pk; pk.x = f2bf(v.x); pk.y = f2bf(v.y); pk.z = f2bf(v.z); pk.w = f2bf(v.w);
        *(ushort4*)(Wbf + (size_t)(dt * 64 + d) * D_SZ + et * 64 + cc) = pk;
        tile[d][cc] = pk.x; tile[d][cc + 1] = pk.y; tile[d][cc + 2] = pk.z; tile[d][cc + 3] = pk.w;
    }
    __syncthreads();
#pragma unroll
    for (int p = 0; p < 4; ++p) {
        const int e = p * 16 + rr;
        ushort4 pk;
        pk.x = tile[cc][e]; pk.y = tile[cc + 1][e]; pk.z = tile[cc + 2][e]; pk.w = tile[cc + 3][e];
        *(ushort4*)(Wt + (size_t)(et * 64 + e) * D_SZ + dt * 64 + cc) = pk;
    }
}

// ---------- features fp32 -> V bf16 [b*n][d] and Vt bf16 [b][d][n] ----------
__global__ __launch_bounds__(256) void convert_feat_k(
    const float* __restrict__ feat, unsigned short* __restrict__ V,
    unsigned short* __restrict__ Vt)
{
    const int nt = blockIdx.x, dt = blockIdx.y, b = blockIdx.z;
    const int t = threadIdx.x;
    __shared__ unsigned short tile[64][72];
    const int rr = t >> 4;
    const int cc = (t & 15) * 4;
#pragma unroll
    for (int p = 0; p < 4; ++p) {
        const int r = p * 16 + rr;
        const size_t grow = (size_t)(b * N_SZ + nt * 64 + r);
        const float4 v = *(const float4*)(feat + grow * D_SZ + dt * 64 + cc);
        ushort4 pk; pk.x = f2bf(v.x); pk.y = f2bf(v.y); pk.z = f2bf(v.z); pk.w = f2bf(v.w);
        *(ushort4*)(V + grow * D_SZ + dt * 64 + cc) = pk;
        tile[r][cc] = pk.x; tile[r][cc + 1] = pk.y; tile[r][cc + 2] = pk.z; tile[r][cc + 3] = pk.w;
    }
    __syncthreads();
#pragma unroll
    for (int p = 0; p < 4; ++p) {
        const int d = p * 16 + rr;
        ushort4 pk;
        pk.x = tile[cc][d]; pk.y = tile[cc + 1][d]; pk.z = tile[cc + 2][d]; pk.w = tile[cc + 3][d];
        *(ushort4*)(Vt + ((size_t)(b * D_SZ + dt * 64 + d)) * N_SZ + nt * 64 + cc) = pk;
    }
}

// ---------- fused: blocks [0,64): ttn = t1bf @ Wbf^T (bf16 out)
// ----------        blocks [64,1088): SS[row] += |V@Wt^T + b|^2 rowwise (no f1 store) ----------
__global__ __launch_bounds__(256) void gemm1f_k(
    const unsigned short* __restrict__ V, const unsigned short* __restrict__ Wt,
    const float* __restrict__ bias, float* __restrict__ SS,
    const unsigned short* __restrict__ t1bf, const unsigned short* __restrict__ Wbf,
    unsigned short* __restrict__ ttn)
{
    __shared__ unsigned short As[128 * 32];
    __shared__ unsigned short Bs[128 * 32];
    f32x4 acc[4][4];
#pragma unroll
    for (int i = 0; i < 4; ++i)
#pragma unroll
        for (int j = 0; j < 4; ++j) acc[i][j] = (f32x4){0.f, 0.f, 0.f, 0.f};
    const int tid = threadIdx.x, lane = tid & 63, w = tid >> 6;
    const int wr = (w >> 1) * 64, wc = (w & 1) * 64, lr = lane & 15, kq = lane >> 4;
    const int blk = blockIdx.x;

    if (blk < 64) {
        const int rowBase = (blk >> 2) * 128;   // m
        const int colBase = (blk & 3) * 128;    // d
        bt_mainloop(t1bf, Wbf, D_SZ, D_SZ, rowBase, colBase, D_SZ, As, Bs, acc);
#pragma unroll
        for (int mi = 0; mi < 4; ++mi) {
            const int r0 = rowBase + wr + mi * 16 + kq * 4;
#pragma unroll
            for (int ni = 0; ni < 4; ++ni) {
                const int c = colBase + wc + ni * 16 + lr;
#pragma unroll
                for (int r = 0; r < 4; ++r)
                    ttn[(size_t)(r0 + r) * D_SZ + c] = f2bf(acc[mi][ni][r]);
            }
        }
    } else {
        const int bb = blk - 64;
        const int rowBase = (bb >> 2) * 128;    // global feature row
        const int colBase = (bb & 3) * 128;     // e
        bt_mainloop(V, Wt, D_SZ, D_SZ, rowBase, colBase, D_SZ, As, Bs, acc);
#pragma unroll
        for (int mi = 0; mi < 4; ++mi) {
            const int r0 = rowBase + wr + mi * 16 + kq * 4;
            float s[4] = {0.f, 0.f, 0.f, 0.f};
#pragma unroll
            for (int ni = 0; ni < 4; ++ni) {
                const int c = colBase + wc + ni * 16 + lr;
                const float bv = bias[c];
#pragma unroll
                for (int r = 0; r < 4; ++r) {
                    const float v = acc[mi][ni][r] + bv;
                    s[r] += v * v;
                }
            }
#pragma unroll
            for (int off = 1; off <= 8; off <<= 1)
#pragma unroll
                for (int r = 0; r < 4; ++r) s[r] += __shfl_xor(s[r], off);
            if (lr == 0) {
#pragma unroll
                for (int r = 0; r < 4; ++r) atomicAdd(&SS[r0 + r], s[r]);
            }
        }
    }
}

// ---------- gemm2: raw = V @ ttn^T; sim = (raw + c2[m]) * invr[n] * invs[m];
// ---------- E = bf16(exp(sim)); L[b][m] += sums.  XCD-swizzled grid. ----------
__global__ __launch_bounds__(256) void gemm2_k(
    const unsigned short* __restrict__ V, const unsigned short* __restrict__ ttn,
    const float* __restrict__ SS, const float* __restrict__ invs,
    const float* __restrict__ c2, unsigned short* __restrict__ E,
    float* __restrict__ L)
{
    __shared__ unsigned short smem[128 * 136];
    unsigned short* As = smem;
    unsigned short* Bs = smem + 4096;
    f32x4 acc[4][4];
#pragma unroll
    for (int i = 0; i < 4; ++i)
#pragma unroll
        for (int j = 0; j < 4; ++j) acc[i][j] = (f32x4){0.f, 0.f, 0.f, 0.f};
    const int tid = threadIdx.x, lane = tid & 63, w = tid >> 6;
    const int wr = (w >> 1) * 64, wc = (w & 1) * 64, lr = lane & 15, kq = lane >> 4;

    const int lin = blockIdx.x;
    const int xcd = lin & 7, slot = lin >> 3;
    const int mt = slot & 15;
    const int rt = (slot >> 4) * 8 + xcd;
    const int rowBase = rt * 128;
    const int colBase = mt * 128;

    bt_mainloop(V, ttn, D_SZ, D_SZ, rowBase, colBase, D_SZ, As, Bs, acc);

    const int b  = rowBase >> 12;
    const int nb = rowBase & 4095;
    unsigned short* Eb = E + (size_t)b * M_SZ * N_SZ;
    unsigned short* P = smem;

    // row norms (global feature rows)
    float invr[4][4];
#pragma unroll
    for (int mi = 0; mi < 4; ++mi) {
        const int r0 = rowBase + wr + mi * 16 + kq * 4;
#pragma unroll
        for (int r = 0; r < 4; ++r)
            invr[mi][r] = 1.f / fmaxf(sqrtf(SS[r0 + r]), 1e-8f);
    }

#pragma unroll
    for (int ni = 0; ni < 4; ++ni) {
        const int mm = wc + ni * 16 + lr;
        const float sm = invs[colBase + mm];
        const float cm = c2[colBase + mm];
        float p = 0.f;
#pragma unroll
        for (int mi = 0; mi < 4; ++mi) {
            const int nn0 = wr + mi * 16 + kq * 4;
            const float e0 = __expf((acc[mi][ni][0] + cm) * invr[mi][0] * sm);
            const float e1 = __expf((acc[mi][ni][1] + cm) * invr[mi][1] * sm);
            const float e2 = __expf((acc[mi][ni][2] + cm) * invr[mi][2] * sm);
            const float e3 = __expf((acc[mi][ni][3] + cm) * invr[mi][3] * sm);
            ushort4 pk; pk.x = f2bf(e0); pk.y = f2bf(e1); pk.z = f2bf(e2); pk.w = f2bf(e3);
            *(ushort4*)(P + mm * 136 + nn0) = pk;
            p += (e0 + e1) + (e2 + e3);
        }
        p += __shfl_down(p, 16);
        p += __shfl_down(p, 32);
        if (lane < 16) atomicAdd(&L[b * M_SZ + colBase + mm], p);
    }
    __syncthreads();

    const int tr = tid >> 4;
    const int tc = (tid & 15) * 8;
#pragma unroll
    for (int j = 0; j < 8; ++j) {
        const int mm = j * 16 + tr;
        bf16x8 v = *(const bf16x8*)(P + mm * 136 + tc);
        *(bf16x8*)(Eb + (size_t)(colBase + mm) * N_SZ + nb + tc) = v;
    }
}

// ---------- gemm3: split-K=2. out[...,:512] += (E @ Vt^T) * invL  (atomic) ----------
// swizzle: lin = dt*256 + g, g = b*32 + mt*2 + kh -> the 4 dt blocks of one
// (b,mt,kh) share lin&7 (same XCD) so the E tile is fetched once per XCD.
__global__ __launch_bounds__(256) void gemm3_k(
    const unsigned short* __restrict__ E, const unsigned short* __restrict__ Vt,
    const float* __restrict__ L, float* __restrict__ out)
{
    __shared__ unsigned short As[128 * 32];
    __shared__ unsigned short Bs[128 * 32];
    f32x4 acc[4][4];
#pragma unroll
    for (int i = 0; i < 4; ++i)
#pragma unroll
        for (int j = 0; j < 4; ++j) acc[i][j] = (f32x4){0.f, 0.f, 0.f, 0.f};
    const int tid = threadIdx.x, lane = tid & 63, w = tid >> 6;
    const int wr = (w >> 1) * 64, wc = (w & 1) * 64, lr = lane & 15, kq = lane >> 4;

    const int lin = blockIdx.x;          // 1024
    const int dt = lin >> 8;
    const int g  = lin & 255;
    const int b  = g >> 5;
    const int mt = (g & 31) >> 1;
    const int kh = g & 1;

    const int rowBase = mt * 128;        // m
    const int colBase = dt * 128;        // d
    const unsigned short* Ab = E  + (size_t)b * M_SZ * N_SZ + (size_t)kh * 2048;
    const unsigned short* Bb = Vt + (size_t)b * D_SZ * N_SZ + (size_t)kh * 2048;
    bt_mainloop(Ab, Bb, N_SZ, N_SZ, rowBase, colBase, 2048, As, Bs, acc);

#pragma unroll
    for (int mi = 0; mi < 4; ++mi) {
        const int r0 = rowBase + wr + mi * 16 + kq * 4;
        float invl[4];
#pragma unroll
        for (int r = 0; r < 4; ++r) invl[r] = 1.f / L[b * M_SZ + r0 + r];
#pragma unroll
        for (int ni = 0; ni < 4; ++ni) {
            const int d = colBase + wc + ni * 16 + lr;
#pragma unroll
            for (int r = 0; r < 4; ++r)
                atomicAdd(&out[((size_t)(b * M_SZ + r0 + r)) * (2 * D_SZ) + d],
                          acc[mi][ni][r] * invl[r]);
        }
    }
}

extern "C" void kernel_launch(void* const* d_in, const int* in_sizes, int n_in,
                              void* d_out, int out_size, void* d_ws, size_t ws_size,
                              hipStream_t stream) {
    const float* features = (const float*)d_in[0];   // [8, 4096, 512]
    const float* text     = (const float*)d_in[1];   // [2, 2048, 512]
    const float* W        = (const float*)d_in[2];   // [512, 512]
    const float* bias     = (const float*)d_in[3];   // [512]
    float* out = (float*)d_out;                      // [8, 2048, 1024]
    char* ws = (char*)d_ws;

    // workspace layout (bytes)
    unsigned short* t1bf = (unsigned short*)(ws + 0);            //  2 MiB [2048][512]
    unsigned short* ttn  = (unsigned short*)(ws + 2097152);      //  2 MiB [2048][512]
    unsigned short* Wt   = (unsigned short*)(ws + 4194304);      // .5 MiB [e][d]
    unsigned short* Wbf  = (unsigned short*)(ws + 4718592);      // .5 MiB [d][e]
    unsigned short* V    = (unsigned short*)(ws + 5242880);      // 32 MiB [32768][512]
    unsigned short* Vt   = (unsigned short*)(ws + 38797312);     // 32 MiB [8][512][4096]
    float*          L    = (float*)(ws + 72351744);              // 64 KiB [8][2048]
    float*          SS   = (float*)(ws + 72417280);              // 128 KiB [32768]
    float*          invs = (float*)(ws + 72548352);              //  8 KiB [2048]
    float*          c2   = (float*)(ws + 72556544);              //  8 KiB [2048]
    unsigned short* E    = (unsigned short*)(ws + 72564736);     // 128 MiB [8][2048][4096]

    hipLaunchKernelGGL(prep_t_k, dim3(M_SZ), dim3(256), 0, stream,
                       text, bias, t1bf, invs, c2, out, L, SS);
    hipLaunchKernelGGL(prep_w_k, dim3(8, 8), dim3(256), 0, stream, W, Wt, Wbf);
    hipLaunchKernelGGL(convert_feat_k, dim3(64, 8, 8), dim3(256), 0, stream, features, V, Vt);
    hipLaunchKernelGGL(gemm1f_k, dim3(1088), dim3(256), 0, stream,
                       V, Wt, bias, SS, t1bf, Wbf, ttn);
    hipLaunchKernelGGL(gemm2_k, dim3(4096), dim3(256), 0, stream,
                       V, ttn, SS, invs, c2, E, L);
    hipLaunchKernelGGL(gemm3_k, dim3(1024), dim3(256), 0, stream, E, Vt, L, out);
}